// Round 16
// baseline (284.078 us; speedup 1.0000x reference)
//
#include <hip/hip_runtime.h>
#include <hip/hip_bf16.h>
#include <math.h>

#define HIDDEN 128
#define EDGE_DIM 16
#define N_HEADS 8
#define QK_SCALE 0.25f
#define LN_EPS 1e-5f
#define EB_SCALE 256.0f
#define EB_INV (1.0f / 256.0f)

using bf16x8 = __attribute__((ext_vector_type(8))) short;
using f32x4 = __attribute__((ext_vector_type(4))) float;
using f32x4v = __attribute__((ext_vector_type(4))) float;
using f32x2 = __attribute__((ext_vector_type(2))) float;
using i32x4 = __attribute__((ext_vector_type(4))) int;
typedef __hip_bfloat16 bf16;

__device__ __forceinline__ float b2f(short u) {
  union { unsigned int i; float f; } c;
  c.i = ((unsigned int)(unsigned short)u) << 16;
  return c.f;
}
__device__ __forceinline__ short f2b(float f) {
  bf16 h = __float2bfloat16(f);
  union { bf16 b; short s; } c;
  c.b = h;
  return c.s;
}
__device__ __forceinline__ unsigned char f2fp8(float f) {
  int pk = __builtin_amdgcn_cvt_pk_fp8_f32(f, f, 0, false);
  return (unsigned char)(pk & 0xff);
}

// ---------------------------------------------------------------------------
// Weight prep: transposed bf16 copies [N][K], fused qkv bias.
// ---------------------------------------------------------------------------
__global__ __launch_bounds__(256) void conv_weights_kernel(
    const float* __restrict__ Wq, const float* __restrict__ Wk, const float* __restrict__ Wv,
    const float* __restrict__ bq, const float* __restrict__ bk, const float* __restrict__ bv,
    const float* __restrict__ Wo, const float* __restrict__ Wf1, const float* __restrict__ Wf2,
    bf16* __restrict__ Wqkv_t, bf16* __restrict__ Wo_t, bf16* __restrict__ Wf1_t,
    bf16* __restrict__ Wf2_t, float* __restrict__ bqkv) {
  int i = blockIdx.x * 256 + threadIdx.x;
  if (i < 49152) {  // Wqkv_t [384][128]
    int n = i >> 7, k = i & 127;
    const float* W = (n < 128) ? Wq : ((n < 256) ? Wk : Wv);
    int nn = n & 127;
    Wqkv_t[i] = __float2bfloat16(W[k * 128 + nn]);
  } else if (i < 65536) {  // Wo_t [128][128]
    int j = i - 49152;
    int n = j >> 7, k = j & 127;
    Wo_t[j] = __float2bfloat16(Wo[k * 128 + n]);
  } else if (i < 98304) {  // Wf1_t [256][128]
    int j = i - 65536;
    int n = j >> 7, k = j & 127;
    Wf1_t[j] = __float2bfloat16(Wf1[k * 256 + n]);
  } else if (i < 131072) {  // Wf2_t [128][256]
    int j = i - 98304;
    int n = j >> 8, k = j & 255;
    Wf2_t[j] = __float2bfloat16(Wf2[k * 128 + n]);
  }
  if (i < 384) bqkv[i] = (i < 128) ? bq[i] : ((i < 256) ? bk[i - 128] : bv[i - 256]);
}

// ---------------------------------------------------------------------------
// MFMA GEMM, 64-row x 128-col block (4 waves = 2 row-halves x 2 col-halves).
// ---------------------------------------------------------------------------
template <int K, int EPI, int OUTBF, int AF32>
__global__ __launch_bounds__(256) void mfma_gemm_kernel(
    const void* __restrict__ Ap, const bf16* __restrict__ Wt,
    const float* __restrict__ bias, void* __restrict__ Cout, int M, int Nc) {
  const int tid = threadIdx.x;
  const int w = tid >> 6, l = tid & 63;
  const int wr = w >> 1, wc = w & 1;
  const int lr = l & 15, lk = l >> 4;
  const int bm = blockIdx.y * 64;
  const int bn = blockIdx.x * 128 + wc * 64;

  f32x4 acc[2][4] = {};
  const int arow0 = bm + wr * 32 + lr;

  for (int k0 = 0; k0 < K; k0 += 128) {
    bf16x8 bfr[4][4];
#pragma unroll
    for (int fn = 0; fn < 4; ++fn) {
      const bf16* wp = Wt + (size_t)(bn + fn * 16 + lr) * K + k0 + lk * 8;
#pragma unroll
      for (int ks = 0; ks < 4; ++ks) bfr[fn][ks] = *(const bf16x8*)(wp + ks * 32);
    }
    bf16x8 afr[2][4];
#pragma unroll
    for (int fr = 0; fr < 2; ++fr) {
      int row = arow0 + fr * 16;
      if (row >= M) row = M - 1;
      if (AF32) {
        const float* ap = (const float*)Ap + (size_t)row * K + k0 + lk * 8;
#pragma unroll
        for (int ks = 0; ks < 4; ++ks) {
          float4 x = *(const float4*)(ap + ks * 32);
          float4 y = *(const float4*)(ap + ks * 32 + 4);
          bf16x8 t;
          t[0] = f2b(x.x); t[1] = f2b(x.y); t[2] = f2b(x.z); t[3] = f2b(x.w);
          t[4] = f2b(y.x); t[5] = f2b(y.y); t[6] = f2b(y.z); t[7] = f2b(y.w);
          afr[fr][ks] = t;
        }
      } else {
        const bf16* ap = (const bf16*)Ap + (size_t)row * K + k0 + lk * 8;
#pragma unroll
        for (int ks = 0; ks < 4; ++ks) afr[fr][ks] = *(const bf16x8*)(ap + ks * 32);
      }
    }
#pragma unroll
    for (int ks = 0; ks < 4; ++ks)
#pragma unroll
      for (int fr = 0; fr < 2; ++fr)
#pragma unroll
        for (int fn = 0; fn < 4; ++fn)
          acc[fr][fn] = __builtin_amdgcn_mfma_f32_16x16x32_bf16(afr[fr][ks], bfr[fn][ks],
                                                                acc[fr][fn], 0, 0, 0);
  }

#pragma unroll
  for (int fn = 0; fn < 4; ++fn) {
    const int col = bn + fn * 16 + lr;
    const float bv = bias[col];
#pragma unroll
    for (int fr = 0; fr < 2; ++fr) {
      const int rbase = bm + wr * 32 + fr * 16 + lk * 4;
#pragma unroll
      for (int r = 0; r < 4; ++r) {
        int row = rbase + r;
        if (row < M) {
          float o = acc[fr][fn][r] + bv;
          if (EPI == 1) o = o / (1.f + __expf(-o));
          if (OUTBF)
            ((bf16*)Cout)[(size_t)row * Nc + col] = __float2bfloat16(o);
          else
            ((float*)Cout)[(size_t)row * Nc + col] = o;
        }
      }
    }
  }
}

// ---------------------------------------------------------------------------
// Fused QKV MFMA GEMM: one block = 64 rows x ALL 384 cols; A fragments
// register-resident across the 3 weight slices. LDS repack -> coalesced out.
// ---------------------------------------------------------------------------
__global__ __launch_bounds__(256) void mfma_gemm_qkv_kernel(
    const float* __restrict__ A, const bf16* __restrict__ Wt,
    const float* __restrict__ bias, bf16* __restrict__ qb,
    unsigned char* __restrict__ kv8, int M) {
  __shared__ __align__(16) char lds[64 * 272];
  const int tid = threadIdx.x;
  const int w = tid >> 6, l = tid & 63;
  const int wr = w >> 1, wc = w & 1;
  const int lr = l & 15, lk = l >> 4;
  const int bm = blockIdx.x * 64;
  const int arow0 = bm + wr * 32 + lr;

  bf16x8 afr[2][4];
#pragma unroll
  for (int fr = 0; fr < 2; ++fr) {
    int row = arow0 + fr * 16;
    if (row >= M) row = M - 1;
    const float* ap = A + (size_t)row * 128 + lk * 8;
#pragma unroll
    for (int ks = 0; ks < 4; ++ks) {
      float4 x = *(const float4*)(ap + ks * 32);
      float4 y = *(const float4*)(ap + ks * 32 + 4);
      bf16x8 t;
      t[0] = f2b(x.x); t[1] = f2b(x.y); t[2] = f2b(x.z); t[3] = f2b(x.w);
      t[4] = f2b(y.x); t[5] = f2b(y.y); t[6] = f2b(y.z); t[7] = f2b(y.w);
      afr[fr][ks] = t;
    }
  }

  const int row2 = tid >> 2, seg = tid & 3;
  const int grow = bm + row2;

#pragma unroll
  for (int s = 0; s < 3; ++s) {
    const int bn = s * 128 + wc * 64;
    bf16x8 bfr[4][4];
#pragma unroll
    for (int fn = 0; fn < 4; ++fn) {
      const bf16* wp = Wt + (size_t)(bn + fn * 16 + lr) * 128 + lk * 8;
#pragma unroll
      for (int ks = 0; ks < 4; ++ks) bfr[fn][ks] = *(const bf16x8*)(wp + ks * 32);
    }
    f32x4 acc[2][4] = {};
#pragma unroll
    for (int ks = 0; ks < 4; ++ks)
#pragma unroll
      for (int fr = 0; fr < 2; ++fr)
#pragma unroll
        for (int fn = 0; fn < 4; ++fn)
          acc[fr][fn] = __builtin_amdgcn_mfma_f32_16x16x32_bf16(afr[fr][ks], bfr[fn][ks],
                                                                acc[fr][fn], 0, 0, 0);

    if (s > 0) __syncthreads();
    if (s == 0) {
      short* sq = (short*)lds;  // row stride 136 shorts (272B)
#pragma unroll
      for (int fn = 0; fn < 4; ++fn) {
        const int col = wc * 64 + fn * 16 + lr;
        const float bv = bias[bn + fn * 16 + lr];
#pragma unroll
        for (int fr = 0; fr < 2; ++fr) {
#pragma unroll
          for (int r = 0; r < 4; ++r) {
            int rl = wr * 32 + fr * 16 + lk * 4 + r;
            sq[rl * 136 + col] = f2b(acc[fr][fn][r] + bv);
          }
        }
      }
    } else {
      unsigned char* s8 = (unsigned char*)lds;  // row stride 144 B
#pragma unroll
      for (int fn = 0; fn < 4; ++fn) {
        const int col = wc * 64 + fn * 16 + lr;
        const float bv = bias[bn + fn * 16 + lr];
#pragma unroll
        for (int fr = 0; fr < 2; ++fr) {
#pragma unroll
          for (int r = 0; r < 4; ++r) {
            int rl = wr * 32 + fr * 16 + lk * 4 + r;
            s8[rl * 144 + col] = f2fp8(acc[fr][fn][r] + bv);
          }
        }
      }
    }
    __syncthreads();

    if (grow < M) {
      if (s == 0) {
        const int4* src = (const int4*)(lds + row2 * 272 + seg * 64);
        int4* dst = (int4*)(qb + (size_t)grow * 128 + seg * 32);
        dst[0] = src[0];
        dst[1] = src[1];
        dst[2] = src[2];
        dst[3] = src[3];
      } else {
        const int4* src = (const int4*)(lds + row2 * 144 + seg * 32);
        int4* dst = (int4*)(kv8 + (size_t)grow * 256 + (s == 1 ? 0 : 128) + seg * 32);
        dst[0] = src[0];
        dst[1] = src[1];
      }
    }
  }
}

// ---------------------------------------------------------------------------
// MFMA GEMM + residual + LayerNorm fused. Nc = 128 fixed, block = 64 rows.
// ---------------------------------------------------------------------------
template <int K>
__global__ __launch_bounds__(256) void mfma_gemm_ln_kernel(
    const bf16* __restrict__ A, const bf16* __restrict__ Wt,
    const float* __restrict__ bias, const float* __restrict__ R,
    const float* __restrict__ gam, const float* __restrict__ bet,
    float* __restrict__ y, bf16* __restrict__ yb, int M) {
  const int tid = threadIdx.x;
  const int w = tid >> 6, l = tid & 63;
  const int wr = w >> 1, wc = w & 1;
  const int lr = l & 15, lk = l >> 4;
  const int bm = blockIdx.x * 64;
  const int bn = wc * 64;

  f32x4 acc[2][4] = {};
  const int arow0 = bm + wr * 32 + lr;

  for (int k0 = 0; k0 < K; k0 += 128) {
    bf16x8 bfr[4][4];
#pragma unroll
    for (int fn = 0; fn < 4; ++fn) {
      const bf16* wp = Wt + (size_t)(bn + fn * 16 + lr) * K + k0 + lk * 8;
#pragma unroll
      for (int ks = 0; ks < 4; ++ks) bfr[fn][ks] = *(const bf16x8*)(wp + ks * 32);
    }
    bf16x8 afr[2][4];
#pragma unroll
    for (int fr = 0; fr < 2; ++fr) {
      int row = arow0 + fr * 16;
      if (row >= M) row = M - 1;
      const bf16* ap = A + (size_t)row * K + k0 + lk * 8;
#pragma unroll
      for (int ks = 0; ks < 4; ++ks) afr[fr][ks] = *(const bf16x8*)(ap + ks * 32);
    }
#pragma unroll
    for (int ks = 0; ks < 4; ++ks)
#pragma unroll
      for (int fr = 0; fr < 2; ++fr)
#pragma unroll
        for (int fn = 0; fn < 4; ++fn)
          acc[fr][fn] = __builtin_amdgcn_mfma_f32_16x16x32_bf16(afr[fr][ks], bfr[fn][ks],
                                                                acc[fr][fn], 0, 0, 0);
  }

  float bv[4], gv[4], ev[4];
#pragma unroll
  for (int fn = 0; fn < 4; ++fn) {
    int col = bn + fn * 16 + lr;
    bv[fn] = bias[col];
    gv[fn] = gam[col];
    ev[fn] = bet[col];
  }
  float ps[2][4], psq[2][4];
#pragma unroll
  for (int fr = 0; fr < 2; ++fr) {
#pragma unroll
    for (int r = 0; r < 4; ++r) {
      int row = bm + wr * 32 + fr * 16 + lk * 4 + r;
      int rrow = (row < M) ? row : (M - 1);
      float s = 0.f, sq = 0.f;
#pragma unroll
      for (int fn = 0; fn < 4; ++fn) {
        int col = bn + fn * 16 + lr;
        float o = acc[fr][fn][r] + bv[fn] + R[(size_t)rrow * HIDDEN + col];
        acc[fr][fn][r] = o;
        s += o;
        sq += o * o;
      }
      ps[fr][r] = s;
      psq[fr][r] = sq;
    }
  }
#pragma unroll
  for (int off = 1; off < 16; off <<= 1) {
#pragma unroll
    for (int fr = 0; fr < 2; ++fr)
#pragma unroll
      for (int r = 0; r < 4; ++r) {
        ps[fr][r] += __shfl_xor(ps[fr][r], off, 64);
        psq[fr][r] += __shfl_xor(psq[fr][r], off, 64);
      }
  }
  __shared__ float s_sum[2][64], s_sq[2][64];
  if (lr == 0) {
#pragma unroll
    for (int fr = 0; fr < 2; ++fr)
#pragma unroll
      for (int r = 0; r < 4; ++r) {
        int rl = wr * 32 + fr * 16 + lk * 4 + r;
        s_sum[wc][rl] = ps[fr][r];
        s_sq[wc][rl] = psq[fr][r];
      }
  }
  __syncthreads();
#pragma unroll
  for (int fr = 0; fr < 2; ++fr) {
#pragma unroll
    for (int r = 0; r < 4; ++r) {
      int rl = wr * 32 + fr * 16 + lk * 4 + r;
      int row = bm + rl;
      float tot = s_sum[0][rl] + s_sum[1][rl];
      float tsq = s_sq[0][rl] + s_sq[1][rl];
      float mean = tot * (1.f / 128.f);
      float var = tsq * (1.f / 128.f) - mean * mean;
      float rstd = rsqrtf(var + LN_EPS);
      if (row < M) {
#pragma unroll
        for (int fn = 0; fn < 4; ++fn) {
          int col = bn + fn * 16 + lr;
          float val = (acc[fr][fn][r] - mean) * rstd * gv[fn] + ev[fn];
          if (y) y[(size_t)row * HIDDEN + col] = val;
          if (yb) yb[(size_t)row * HIDDEN + col] = __float2bfloat16(val);
        }
      }
    }
  }
}

// ---------------------------------------------------------------------------
// CSR build: histogram -> parallel 3-kernel scan -> place (4B eid scatter)
// ---------------------------------------------------------------------------
__global__ void hist_kernel(const int* __restrict__ dst, int* __restrict__ counts, int E) {
  int e = blockIdx.x * blockDim.x + threadIdx.x;
  if (e < E) atomicAdd(&counts[dst[e]], 1);
}

__device__ __forceinline__ int wave_incl_scan(int x, int lane) {
  int incl = x;
#pragma unroll
  for (int off = 1; off < 64; off <<= 1) {
    int y = __shfl_up(incl, off, 64);
    if (lane >= off) incl += y;
  }
  return incl;
}

__global__ __launch_bounds__(256) void scan_block_kernel(const int* __restrict__ counts,
                                                         int* __restrict__ offs,
                                                         int* __restrict__ btot, int N) {
  __shared__ int s4[4];
  int tid = threadIdx.x;
  int i = blockIdx.x * 256 + tid;
  int lane = tid & 63, wv = tid >> 6;
  int x = (i < N) ? counts[i] : 0;
  int incl = wave_incl_scan(x, lane);
  if (lane == 63) s4[wv] = incl;
  __syncthreads();
  if (tid == 0) {
    int s = 0;
#pragma unroll
    for (int j = 0; j < 4; ++j) { int t = s4[j]; s4[j] = s; s += t; }
    btot[blockIdx.x] = s;
  }
  __syncthreads();
  if (i < N) offs[i] = s4[wv] + incl - x;
}

__global__ __launch_bounds__(256) void scan_tot_kernel(int* __restrict__ btot, int nb) {
  __shared__ int s4[4];
  __shared__ int carry;
  int tid = threadIdx.x;
  int lane = tid & 63, wv = tid >> 6;
  if (tid == 0) carry = 0;
  __syncthreads();
  for (int c0 = 0; c0 < nb; c0 += 256) {
    int i = c0 + tid;
    int x = (i < nb) ? btot[i] : 0;
    int incl = wave_incl_scan(x, lane);
    if (lane == 63) s4[wv] = incl;
    __syncthreads();
    if (tid == 0) {
      int s = 0;
#pragma unroll
      for (int j = 0; j < 4; ++j) { int t = s4[j]; s4[j] = s; s += t; }
    }
    __syncthreads();
    int base = carry + s4[wv];
    if (i < nb) btot[i] = base + incl - x;
    __syncthreads();
    if (tid == 255) carry = base + incl;
    __syncthreads();
  }
}

__global__ __launch_bounds__(256) void scan_add_kernel(int* __restrict__ offs,
                                                       const int* __restrict__ btot,
                                                       int N, int E) {
  int i = blockIdx.x * 256 + threadIdx.x;
  if (i < N) offs[i] += btot[blockIdx.x];
  if (i == 0) offs[N] = E;
}

// ---------------------------------------------------------------------------
// Edge-bias MLP, SEQUENTIAL record write: es_seq[e] = {src, eb-lo, eb-hi, 0}.
// Pure streaming kernel: no dst read, no atomics, coalesced nt stores.
// ---------------------------------------------------------------------------
__global__ __launch_bounds__(256) void mlp_seq_kernel(
    const int* __restrict__ src, const float* __restrict__ ef,
    const float* __restrict__ Wb1, const float* __restrict__ bb1,
    const float* __restrict__ Wb2, const float* __restrict__ bb2,
    i32x4* __restrict__ es_seq, int E) {
  __shared__ float w1[128], w2[64], b1[8], b2[8];
  int tid = threadIdx.x;
  if (tid < 128) w1[tid] = Wb1[tid];
  else if (tid < 192) w2[tid - 128] = Wb2[tid - 128];
  else if (tid < 200) b1[tid - 192] = bb1[tid - 192];
  else if (tid < 208) b2[tid - 200] = bb2[tid - 200];
  __syncthreads();

  int e = blockIdx.x * 256 + tid;
  if (e >= E) return;

  const f32x4v* p4 = (const f32x4v*)(ef + (size_t)e * 16);
  f32x4v f0 = __builtin_nontemporal_load(p4 + 0);
  f32x4v f1 = __builtin_nontemporal_load(p4 + 1);
  f32x4v f2 = __builtin_nontemporal_load(p4 + 2);
  f32x4v f3 = __builtin_nontemporal_load(p4 + 3);
  float x[16] = {f0[0], f0[1], f0[2], f0[3], f1[0], f1[1], f1[2], f1[3],
                 f2[0], f2[1], f2[2], f2[3], f3[0], f3[1], f3[2], f3[3]};

  float h[8];
#pragma unroll
  for (int j = 0; j < 8; ++j) h[j] = b1[j];
#pragma unroll
  for (int i = 0; i < 16; ++i) {
    float xi = x[i];
#pragma unroll
    for (int j = 0; j < 8; ++j) h[j] = fmaf(xi, w1[i * 8 + j], h[j]);
  }
#pragma unroll
  for (int j = 0; j < 8; ++j) h[j] = h[j] / (1.f + __expf(-h[j]));

  float o[8];
#pragma unroll
  for (int j = 0; j < 8; ++j) o[j] = b2[j];
#pragma unroll
  for (int jj = 0; jj < 8; ++jj) {
    float hj = h[jj];
#pragma unroll
    for (int j = 0; j < 8; ++j) o[j] = fmaf(hj, w2[jj * 8 + j], o[j]);
  }

  int lo = __builtin_amdgcn_cvt_pk_fp8_f32(o[0] * EB_SCALE, o[1] * EB_SCALE, 0, false);
  lo = __builtin_amdgcn_cvt_pk_fp8_f32(o[2] * EB_SCALE, o[3] * EB_SCALE, lo, true);
  int hi = __builtin_amdgcn_cvt_pk_fp8_f32(o[4] * EB_SCALE, o[5] * EB_SCALE, 0, false);
  hi = __builtin_amdgcn_cvt_pk_fp8_f32(o[6] * EB_SCALE, o[7] * EB_SCALE, hi, true);

  i32x4 rec;
  rec[0] = src[e]; rec[1] = lo; rec[2] = hi; rec[3] = 0;
  __builtin_nontemporal_store(rec, es_seq + e);
}

// Place: the ONLY random write is a 4-byte eid into the 3.2MB eid_csr table
// (16 slots/line, ~400KB/XCD -> L2-resident -> line merging works).
__global__ __launch_bounds__(256) void place_kernel(
    const int* __restrict__ dst, const int* __restrict__ offs,
    int* __restrict__ cursor, int* __restrict__ eid_csr, int E) {
  int e = blockIdx.x * 256 + threadIdx.x;
  if (e >= E) return;
  int d = dst[e];
  int p = offs[d] + atomicAdd(&cursor[d], 1);
  eid_csr[p] = e;
}

// ---------------------------------------------------------------------------
// Attention: 1 wave per dst node, 8 edges in flight, 8 lanes/edge.
// eid_csr read sequentially; es_seq[eid] (16B) and kv8[src] (256B) gathered.
// Next iteration's eid->record chain is software-prefetched.
// ---------------------------------------------------------------------------
__global__ __launch_bounds__(256) void node_attn_kernel(
    const bf16* __restrict__ qb, const unsigned char* __restrict__ kv8,
    const i32x4* __restrict__ es_seq, const int* __restrict__ eid_csr,
    const int* __restrict__ offs, bf16* __restrict__ agg, int Nn) {
  int n = blockIdx.x * 4 + (threadIdx.x >> 6);
  if (n >= Nn) return;
  int l = threadIdx.x & 63;
  int g = l >> 3;   // edge slot 0..7
  int il = l & 7;   // head index

  int s0 = offs[n], s1 = offs[n + 1];
  bf16* orow = agg + (size_t)n * HIDDEN + il * 16;
  if (s0 >= s1) {  // isolated node: zero output
    if (g == 0) {
      bf16x8 z = {};
      *(bf16x8*)(orow) = z;
      *(bf16x8*)(orow + 8) = z;
    }
    return;
  }

  const bf16* qrow = qb + (size_t)n * 128 + il * 16;
  bf16x8 qa = *(const bf16x8*)(qrow);
  bf16x8 qb8 = *(const bf16x8*)(qrow + 8);
  float qf[16];
#pragma unroll
  for (int j = 0; j < 8; ++j) {
    qf[j] = b2f(qa[j]) * QK_SCALE;
    qf[8 + j] = b2f(qb8[j]) * QK_SCALE;
  }

  float lsum = 0.f;
  float acc[16] = {};
  const int ebshift = (il & 2) << 3;  // 0 or 16

  int pc0 = (s0 + g < s1) ? (s0 + g) : (s1 - 1);
  i32x4 rec = es_seq[eid_csr[pc0]];

  for (int p0 = s0; p0 < s1; p0 += 8) {
    bool valid = (p0 + g) < s1;
    i32x4 cur = rec;
    int pn = p0 + 8 + g;
    if (pn < s1) rec = es_seq[eid_csr[pn]];  // prefetch next chain

    int cs = cur[0];
    unsigned ebw = (unsigned)((il < 4) ? cur[1] : cur[2]);
    f32x2 ebp = __builtin_amdgcn_cvt_pk_f32_fp8(ebw >> ebshift, false);
    float ebv = ((il & 1) ? ebp[1] : ebp[0]) * EB_INV;

    const unsigned char* kvrow = kv8 + (size_t)cs * 256 + il * 16;
    i32x4 kw = *(const i32x4*)(kvrow);
    i32x4 vw = *(const i32x4*)(kvrow + 128);

    float prod = 0.f;
#pragma unroll
    for (int w2 = 0; w2 < 4; ++w2) {
      f32x2 lo = __builtin_amdgcn_cvt_pk_f32_fp8(kw[w2], false);
      f32x2 hi = __builtin_amdgcn_cvt_pk_f32_fp8(kw[w2], true);
      prod = fmaf(qf[w2 * 4 + 0], lo[0], prod);
      prod = fmaf(qf[w2 * 4 + 1], lo[1], prod);
      prod = fmaf(qf[w2 * 4 + 2], hi[0], prod);
      prod = fmaf(qf[w2 * 4 + 3], hi[1], prod);
    }
    float pe = valid ? __expf(prod + ebv) : 0.f;
    lsum += pe;
#pragma unroll
    for (int w2 = 0; w2 < 4; ++w2) {
      f32x2 lo = __builtin_amdgcn_cvt_pk_f32_fp8(vw[w2], false);
      f32x2 hi = __builtin_amdgcn_cvt_pk_f32_fp8(vw[w2], true);
      acc[w2 * 4 + 0] = fmaf(pe, lo[0], acc[w2 * 4 + 0]);
      acc[w2 * 4 + 1] = fmaf(pe, lo[1], acc[w2 * 4 + 1]);
      acc[w2 * 4 + 2] = fmaf(pe, hi[0], acc[w2 * 4 + 2]);
      acc[w2 * 4 + 3] = fmaf(pe, hi[1], acc[w2 * 4 + 3]);
    }
  }

  // merge the 8 edge-slot partials (lanes xor 8,16,32 share the same head)
#pragma unroll
  for (int off = 8; off < 64; off <<= 1) {
    lsum += __shfl_xor(lsum, off, 64);
#pragma unroll
    for (int j = 0; j < 16; ++j) acc[j] += __shfl_xor(acc[j], off, 64);
  }

  if (g == 0) {
    float inv = (lsum > 0.f) ? 1.f / lsum : 0.f;
    bf16x8 o0, o1;
#pragma unroll
    for (int j = 0; j < 8; ++j) {
      o0[j] = f2b(acc[j] * inv);
      o1[j] = f2b(acc[8 + j] * inv);
    }
    *(bf16x8*)(orow) = o0;
    *(bf16x8*)(orow + 8) = o1;
  }
}

// ---------------------------------------------------------------------------
extern "C" void kernel_launch(void* const* d_in, const int* in_sizes, int n_in,
                              void* d_out, int out_size, void* d_ws, size_t ws_size,
                              hipStream_t stream) {
  const float* nf = (const float*)d_in[0];
  const int* ei = (const int*)d_in[1];
  const float* ef = (const float*)d_in[2];
  const float* Wq = (const float*)d_in[3];
  const float* bq = (const float*)d_in[4];
  const float* Wk = (const float*)d_in[5];
  const float* bk_ = (const float*)d_in[6];
  const float* Wv = (const float*)d_in[7];
  const float* bv = (const float*)d_in[8];
  const float* Wb1 = (const float*)d_in[9];
  const float* bb1 = (const float*)d_in[10];
  const float* Wb2 = (const float*)d_in[11];
  const float* bb2 = (const float*)d_in[12];
  const float* Wo = (const float*)d_in[13];
  const float* bo = (const float*)d_in[14];
  const float* Wf1 = (const float*)d_in[15];
  const float* bf1 = (const float*)d_in[16];
  const float* Wf2 = (const float*)d_in[17];
  const float* bf2 = (const float*)d_in[18];
  const float* g1 = (const float*)d_in[19];
  const float* be1 = (const float*)d_in[20];
  const float* g2 = (const float*)d_in[21];
  const float* be2 = (const float*)d_in[22];

  const int N = in_sizes[0] / HIDDEN;
  const int E = in_sizes[2] / EDGE_DIM;
  const int* srcA = ei;
  const int* dstA = ei + E;

  char* base = (char*)d_ws;
  size_t off = 0;
  auto alloc = [&](size_t bytes) {
    off = (off + 255) & ~(size_t)255;
    char* p = base + off;
    off += bytes;
    return p;
  };

  // region B: qb [N,128]bf16 + kv8 [N,256]u8 -> hbuf [N,256] bf16 overlay
  size_t qb_bytes = (size_t)N * 128 * 2;
  size_t kv_bytes = (size_t)N * 256;
  size_t hb_bytes = (size_t)N * 256 * 2;
  char* regB = alloc(hb_bytes > qb_bytes + kv_bytes ? hb_bytes : qb_bytes + kv_bytes);
  bf16* qb = (bf16*)regB;
  unsigned char* kv8 = (unsigned char*)(regB + qb_bytes);
  bf16* hbuf = (bf16*)regB;
  // standalone
  bf16* agg = (bf16*)alloc((size_t)N * HIDDEN * 2);
  float* x1 = (float*)alloc((size_t)N * HIDDEN * 4);
  bf16* x1b = (bf16*)alloc((size_t)N * HIDDEN * 2);
  i32x4* es_seq = (i32x4*)alloc((size_t)E * 16);
  int* eid_csr = (int*)alloc((size_t)E * 4);
  int* counts = (int*)alloc((size_t)N * 8);  // counts + cursor, one memset
  int* cursor = counts + N;
  int* offs = (int*)alloc((size_t)(N + 1) * 4);
  const int nb = (N + 255) / 256;
  int* btot = (int*)alloc((size_t)nb * 4);
  // weights
  bf16* Wqkv_t = (bf16*)alloc(384 * 128 * 2);
  bf16* Wo_t = (bf16*)alloc(128 * 128 * 2);
  bf16* Wf1_t = (bf16*)alloc(256 * 128 * 2);
  bf16* Wf2_t = (bf16*)alloc(128 * 256 * 2);
  float* bqkv = (float*)alloc(384 * 4);

  float* outp = (float*)d_out;
  const int mb64 = (N + 63) / 64;
  const int eblocks = (E + 255) / 256;

  conv_weights_kernel<<<512, 256, 0, stream>>>(Wq, Wk, Wv, bq, bk_, bv, Wo, Wf1, Wf2,
                                               Wqkv_t, Wo_t, Wf1_t, Wf2_t, bqkv);

  // fused QKV projection (single grid; A fragments register-resident x3 slices)
  mfma_gemm_qkv_kernel<<<mb64, 256, 0, stream>>>(nf, Wqkv_t, bqkv, qb, kv8, N);

  // edge-bias MLP -> sequential records (pure streaming)
  mlp_seq_kernel<<<eblocks, 256, 0, stream>>>(srcA, ef, Wb1, bb1, Wb2, bb2, es_seq, E);

  // CSR build + 4B eid placement
  hipMemsetAsync(counts, 0, (size_t)N * 8, stream);
  hist_kernel<<<eblocks, 256, 0, stream>>>(dstA, counts, E);
  scan_block_kernel<<<nb, 256, 0, stream>>>(counts, offs, btot, N);
  scan_tot_kernel<<<1, 256, 0, stream>>>(btot, nb);
  scan_add_kernel<<<nb, 256, 0, stream>>>(offs, btot, N, E);
  place_kernel<<<eblocks, 256, 0, stream>>>(dstA, offs, cursor, eid_csr, E);

  // attention + aggregation (fp8 K/V gather; eid->record chain prefetched)
  node_attn_kernel<<<(N + 3) / 4, 256, 0, stream>>>(qb, kv8, es_seq, eid_csr, offs,
                                                    agg, N);

  // out proj + residual + LN1 (fused) -> x1 fp32 + x1b bf16
  mfma_gemm_ln_kernel<128><<<mb64, 256, 0, stream>>>(agg, Wo_t, bo, nf, g1, be1, x1, x1b, N);

  // FFN1 (silu, bf16 out)
  mfma_gemm_kernel<128, 1, 1, 0><<<dim3(2, mb64), 256, 0, stream>>>(
      x1b, Wf1_t, bf1, hbuf, N, 256);

  // FFN2 + residual + LN2 (fused) -> output fp32
  mfma_gemm_ln_kernel<256><<<mb64, 256, 0, stream>>>(hbuf, Wf2_t, bf2, x1, g2, be2,
                                                     outp, nullptr, N);
}

// Round 17
// 265.152 us; speedup vs baseline: 1.0714x; 1.0714x over previous
//
#include <hip/hip_runtime.h>
#include <hip/hip_bf16.h>
#include <math.h>

#define HIDDEN 128
#define EDGE_DIM 16
#define N_HEADS 8
#define QK_SCALE 0.25f
#define LN_EPS 1e-5f
#define EB_SCALE 256.0f
#define EB_INV (1.0f / 256.0f)

using bf16x8 = __attribute__((ext_vector_type(8))) short;
using f32x4 = __attribute__((ext_vector_type(4))) float;
using f32x4v = __attribute__((ext_vector_type(4))) float;
using f32x2 = __attribute__((ext_vector_type(2))) float;
using i32x4 = __attribute__((ext_vector_type(4))) int;
typedef __hip_bfloat16 bf16;

__device__ __forceinline__ float b2f(short u) {
  union { unsigned int i; float f; } c;
  c.i = ((unsigned int)(unsigned short)u) << 16;
  return c.f;
}
__device__ __forceinline__ short f2b(float f) {
  bf16 h = __float2bfloat16(f);
  union { bf16 b; short s; } c;
  c.b = h;
  return c.s;
}
__device__ __forceinline__ unsigned char f2fp8(float f) {
  int pk = __builtin_amdgcn_cvt_pk_fp8_f32(f, f, 0, false);
  return (unsigned char)(pk & 0xff);
}

// ---------------------------------------------------------------------------
// Weight prep: transposed bf16 copies [N][K], fused qkv bias.
// ---------------------------------------------------------------------------
__global__ __launch_bounds__(256) void conv_weights_kernel(
    const float* __restrict__ Wq, const float* __restrict__ Wk, const float* __restrict__ Wv,
    const float* __restrict__ bq, const float* __restrict__ bk, const float* __restrict__ bv,
    const float* __restrict__ Wo, const float* __restrict__ Wf1, const float* __restrict__ Wf2,
    bf16* __restrict__ Wqkv_t, bf16* __restrict__ Wo_t, bf16* __restrict__ Wf1_t,
    bf16* __restrict__ Wf2_t, float* __restrict__ bqkv) {
  int i = blockIdx.x * 256 + threadIdx.x;
  if (i < 49152) {  // Wqkv_t [384][128]
    int n = i >> 7, k = i & 127;
    const float* W = (n < 128) ? Wq : ((n < 256) ? Wk : Wv);
    int nn = n & 127;
    Wqkv_t[i] = __float2bfloat16(W[k * 128 + nn]);
  } else if (i < 65536) {  // Wo_t [128][128]
    int j = i - 49152;
    int n = j >> 7, k = j & 127;
    Wo_t[j] = __float2bfloat16(Wo[k * 128 + n]);
  } else if (i < 98304) {  // Wf1_t [256][128]
    int j = i - 65536;
    int n = j >> 7, k = j & 127;
    Wf1_t[j] = __float2bfloat16(Wf1[k * 256 + n]);
  } else if (i < 131072) {  // Wf2_t [128][256]
    int j = i - 98304;
    int n = j >> 8, k = j & 255;
    Wf2_t[j] = __float2bfloat16(Wf2[k * 128 + n]);
  }
  if (i < 384) bqkv[i] = (i < 128) ? bq[i] : ((i < 256) ? bk[i - 128] : bv[i - 256]);
}

// ---------------------------------------------------------------------------
// MFMA GEMM, 64-row x 128-col block (4 waves = 2 row-halves x 2 col-halves).
// ---------------------------------------------------------------------------
template <int K, int EPI, int OUTBF>
__global__ __launch_bounds__(256) void mfma_gemm_kernel(
    const bf16* __restrict__ A, const bf16* __restrict__ Wt,
    const float* __restrict__ bias, void* __restrict__ Cout, int M, int Nc) {
  const int tid = threadIdx.x;
  const int w = tid >> 6, l = tid & 63;
  const int wr = w >> 1, wc = w & 1;
  const int lr = l & 15, lk = l >> 4;
  const int bm = blockIdx.y * 64;
  const int bn = blockIdx.x * 128 + wc * 64;

  f32x4 acc[2][4] = {};
  const int arow0 = bm + wr * 32 + lr;

  for (int k0 = 0; k0 < K; k0 += 128) {
    bf16x8 bfr[4][4];
#pragma unroll
    for (int fn = 0; fn < 4; ++fn) {
      const bf16* wp = Wt + (size_t)(bn + fn * 16 + lr) * K + k0 + lk * 8;
#pragma unroll
      for (int ks = 0; ks < 4; ++ks) bfr[fn][ks] = *(const bf16x8*)(wp + ks * 32);
    }
    bf16x8 afr[2][4];
#pragma unroll
    for (int fr = 0; fr < 2; ++fr) {
      int row = arow0 + fr * 16;
      if (row >= M) row = M - 1;
      const bf16* ap = A + (size_t)row * K + k0 + lk * 8;
#pragma unroll
      for (int ks = 0; ks < 4; ++ks) afr[fr][ks] = *(const bf16x8*)(ap + ks * 32);
    }
#pragma unroll
    for (int ks = 0; ks < 4; ++ks)
#pragma unroll
      for (int fr = 0; fr < 2; ++fr)
#pragma unroll
        for (int fn = 0; fn < 4; ++fn)
          acc[fr][fn] = __builtin_amdgcn_mfma_f32_16x16x32_bf16(afr[fr][ks], bfr[fn][ks],
                                                                acc[fr][fn], 0, 0, 0);
  }

#pragma unroll
  for (int fn = 0; fn < 4; ++fn) {
    const int col = bn + fn * 16 + lr;
    const float bv = bias[col];
#pragma unroll
    for (int fr = 0; fr < 2; ++fr) {
      const int rbase = bm + wr * 32 + fr * 16 + lk * 4;
#pragma unroll
      for (int r = 0; r < 4; ++r) {
        int row = rbase + r;
        if (row < M) {
          float o = acc[fr][fn][r] + bv;
          if (EPI == 1) o = o / (1.f + __expf(-o));
          if (OUTBF)
            ((bf16*)Cout)[(size_t)row * Nc + col] = __float2bfloat16(o);
          else
            ((float*)Cout)[(size_t)row * Nc + col] = o;
        }
      }
    }
  }
}

// ---------------------------------------------------------------------------
// Fused QKV MFMA GEMM: one block = 64 rows x ALL 384 cols; A fragments
// register-resident across the 3 weight slices. LDS repack -> coalesced out.
// ---------------------------------------------------------------------------
__global__ __launch_bounds__(256) void mfma_gemm_qkv_kernel(
    const float* __restrict__ A, const bf16* __restrict__ Wt,
    const float* __restrict__ bias, bf16* __restrict__ qb,
    unsigned char* __restrict__ kv8, int M) {
  __shared__ __align__(16) char lds[64 * 272];
  const int tid = threadIdx.x;
  const int w = tid >> 6, l = tid & 63;
  const int wr = w >> 1, wc = w & 1;
  const int lr = l & 15, lk = l >> 4;
  const int bm = blockIdx.x * 64;
  const int arow0 = bm + wr * 32 + lr;

  bf16x8 afr[2][4];
#pragma unroll
  for (int fr = 0; fr < 2; ++fr) {
    int row = arow0 + fr * 16;
    if (row >= M) row = M - 1;
    const float* ap = A + (size_t)row * 128 + lk * 8;
#pragma unroll
    for (int ks = 0; ks < 4; ++ks) {
      float4 x = *(const float4*)(ap + ks * 32);
      float4 y = *(const float4*)(ap + ks * 32 + 4);
      bf16x8 t;
      t[0] = f2b(x.x); t[1] = f2b(x.y); t[2] = f2b(x.z); t[3] = f2b(x.w);
      t[4] = f2b(y.x); t[5] = f2b(y.y); t[6] = f2b(y.z); t[7] = f2b(y.w);
      afr[fr][ks] = t;
    }
  }

  const int row2 = tid >> 2, seg = tid & 3;
  const int grow = bm + row2;

#pragma unroll
  for (int s = 0; s < 3; ++s) {
    const int bn = s * 128 + wc * 64;
    bf16x8 bfr[4][4];
#pragma unroll
    for (int fn = 0; fn < 4; ++fn) {
      const bf16* wp = Wt + (size_t)(bn + fn * 16 + lr) * 128 + lk * 8;
#pragma unroll
      for (int ks = 0; ks < 4; ++ks) bfr[fn][ks] = *(const bf16x8*)(wp + ks * 32);
    }
    f32x4 acc[2][4] = {};
#pragma unroll
    for (int ks = 0; ks < 4; ++ks)
#pragma unroll
      for (int fr = 0; fr < 2; ++fr)
#pragma unroll
        for (int fn = 0; fn < 4; ++fn)
          acc[fr][fn] = __builtin_amdgcn_mfma_f32_16x16x32_bf16(afr[fr][ks], bfr[fn][ks],
                                                                acc[fr][fn], 0, 0, 0);

    if (s > 0) __syncthreads();
    if (s == 0) {
      short* sq = (short*)lds;  // row stride 136 shorts (272B)
#pragma unroll
      for (int fn = 0; fn < 4; ++fn) {
        const int col = wc * 64 + fn * 16 + lr;
        const float bv = bias[bn + fn * 16 + lr];
#pragma unroll
        for (int fr = 0; fr < 2; ++fr) {
#pragma unroll
          for (int r = 0; r < 4; ++r) {
            int rl = wr * 32 + fr * 16 + lk * 4 + r;
            sq[rl * 136 + col] = f2b(acc[fr][fn][r] + bv);
          }
        }
      }
    } else {
      unsigned char* s8 = (unsigned char*)lds;  // row stride 144 B
#pragma unroll
      for (int fn = 0; fn < 4; ++fn) {
        const int col = wc * 64 + fn * 16 + lr;
        const float bv = bias[bn + fn * 16 + lr];
#pragma unroll
        for (int fr = 0; fr < 2; ++fr) {
#pragma unroll
          for (int r = 0; r < 4; ++r) {
            int rl = wr * 32 + fr * 16 + lk * 4 + r;
            s8[rl * 144 + col] = f2fp8(acc[fr][fn][r] + bv);
          }
        }
      }
    }
    __syncthreads();

    if (grow < M) {
      if (s == 0) {
        const int4* src = (const int4*)(lds + row2 * 272 + seg * 64);
        int4* dst = (int4*)(qb + (size_t)grow * 128 + seg * 32);
        dst[0] = src[0];
        dst[1] = src[1];
        dst[2] = src[2];
        dst[3] = src[3];
      } else {
        const int4* src = (const int4*)(lds + row2 * 144 + seg * 32);
        int4* dst = (int4*)(kv8 + (size_t)grow * 256 + (s == 1 ? 0 : 128) + seg * 32);
        dst[0] = src[0];
        dst[1] = src[1];
      }
    }
  }
}

// ---------------------------------------------------------------------------
// MFMA GEMM + residual + LayerNorm fused. Nc = 128 fixed, block = 64 rows.
// RBF: residual R is bf16 (else fp32). Writes y fp32 and/or yb bf16.
// ---------------------------------------------------------------------------
template <int K, int RBF>
__global__ __launch_bounds__(256) void mfma_gemm_ln_kernel(
    const bf16* __restrict__ A, const bf16* __restrict__ Wt,
    const float* __restrict__ bias, const void* __restrict__ Rp,
    const float* __restrict__ gam, const float* __restrict__ bet,
    float* __restrict__ y, bf16* __restrict__ yb, int M) {
  const int tid = threadIdx.x;
  const int w = tid >> 6, l = tid & 63;
  const int wr = w >> 1, wc = w & 1;
  const int lr = l & 15, lk = l >> 4;
  const int bm = blockIdx.x * 64;
  const int bn = wc * 64;

  f32x4 acc[2][4] = {};
  const int arow0 = bm + wr * 32 + lr;

  for (int k0 = 0; k0 < K; k0 += 128) {
    bf16x8 bfr[4][4];
#pragma unroll
    for (int fn = 0; fn < 4; ++fn) {
      const bf16* wp = Wt + (size_t)(bn + fn * 16 + lr) * K + k0 + lk * 8;
#pragma unroll
      for (int ks = 0; ks < 4; ++ks) bfr[fn][ks] = *(const bf16x8*)(wp + ks * 32);
    }
    bf16x8 afr[2][4];
#pragma unroll
    for (int fr = 0; fr < 2; ++fr) {
      int row = arow0 + fr * 16;
      if (row >= M) row = M - 1;
      const bf16* ap = A + (size_t)row * K + k0 + lk * 8;
#pragma unroll
      for (int ks = 0; ks < 4; ++ks) afr[fr][ks] = *(const bf16x8*)(ap + ks * 32);
    }
#pragma unroll
    for (int ks = 0; ks < 4; ++ks)
#pragma unroll
      for (int fr = 0; fr < 2; ++fr)
#pragma unroll
        for (int fn = 0; fn < 4; ++fn)
          acc[fr][fn] = __builtin_amdgcn_mfma_f32_16x16x32_bf16(afr[fr][ks], bfr[fn][ks],
                                                                acc[fr][fn], 0, 0, 0);
  }

  float bv[4], gv[4], ev[4];
#pragma unroll
  for (int fn = 0; fn < 4; ++fn) {
    int col = bn + fn * 16 + lr;
    bv[fn] = bias[col];
    gv[fn] = gam[col];
    ev[fn] = bet[col];
  }
  float ps[2][4], psq[2][4];
#pragma unroll
  for (int fr = 0; fr < 2; ++fr) {
#pragma unroll
    for (int r = 0; r < 4; ++r) {
      int row = bm + wr * 32 + fr * 16 + lk * 4 + r;
      int rrow = (row < M) ? row : (M - 1);
      float s = 0.f, sq = 0.f;
#pragma unroll
      for (int fn = 0; fn < 4; ++fn) {
        int col = bn + fn * 16 + lr;
        float rv;
        if (RBF)
          rv = b2f(((const short*)Rp)[(size_t)rrow * HIDDEN + col]);
        else
          rv = ((const float*)Rp)[(size_t)rrow * HIDDEN + col];
        float o = acc[fr][fn][r] + bv[fn] + rv;
        acc[fr][fn][r] = o;
        s += o;
        sq += o * o;
      }
      ps[fr][r] = s;
      psq[fr][r] = sq;
    }
  }
#pragma unroll
  for (int off = 1; off < 16; off <<= 1) {
#pragma unroll
    for (int fr = 0; fr < 2; ++fr)
#pragma unroll
      for (int r = 0; r < 4; ++r) {
        ps[fr][r] += __shfl_xor(ps[fr][r], off, 64);
        psq[fr][r] += __shfl_xor(psq[fr][r], off, 64);
      }
  }
  __shared__ float s_sum[2][64], s_sq[2][64];
  if (lr == 0) {
#pragma unroll
    for (int fr = 0; fr < 2; ++fr)
#pragma unroll
      for (int r = 0; r < 4; ++r) {
        int rl = wr * 32 + fr * 16 + lk * 4 + r;
        s_sum[wc][rl] = ps[fr][r];
        s_sq[wc][rl] = psq[fr][r];
      }
  }
  __syncthreads();
#pragma unroll
  for (int fr = 0; fr < 2; ++fr) {
#pragma unroll
    for (int r = 0; r < 4; ++r) {
      int rl = wr * 32 + fr * 16 + lk * 4 + r;
      int row = bm + rl;
      float tot = s_sum[0][rl] + s_sum[1][rl];
      float tsq = s_sq[0][rl] + s_sq[1][rl];
      float mean = tot * (1.f / 128.f);
      float var = tsq * (1.f / 128.f) - mean * mean;
      float rstd = rsqrtf(var + LN_EPS);
      if (row < M) {
#pragma unroll
        for (int fn = 0; fn < 4; ++fn) {
          int col = bn + fn * 16 + lr;
          float val = (acc[fr][fn][r] - mean) * rstd * gv[fn] + ev[fn];
          if (y) y[(size_t)row * HIDDEN + col] = val;
          if (yb) yb[(size_t)row * HIDDEN + col] = __float2bfloat16(val);
        }
      }
    }
  }
}

// ---------------------------------------------------------------------------
// CSR build: histogram -> parallel 3-kernel scan -> fused scatter+edge-MLP
// ---------------------------------------------------------------------------
__global__ void hist_kernel(const int* __restrict__ dst, int* __restrict__ counts, int E) {
  int e = blockIdx.x * blockDim.x + threadIdx.x;
  if (e < E) atomicAdd(&counts[dst[e]], 1);
}

__device__ __forceinline__ int wave_incl_scan(int x, int lane) {
  int incl = x;
#pragma unroll
  for (int off = 1; off < 64; off <<= 1) {
    int y = __shfl_up(incl, off, 64);
    if (lane >= off) incl += y;
  }
  return incl;
}

__global__ __launch_bounds__(256) void scan_block_kernel(const int* __restrict__ counts,
                                                         int* __restrict__ offs,
                                                         int* __restrict__ btot, int N) {
  __shared__ int s4[4];
  int tid = threadIdx.x;
  int i = blockIdx.x * 256 + tid;
  int lane = tid & 63, wv = tid >> 6;
  int x = (i < N) ? counts[i] : 0;
  int incl = wave_incl_scan(x, lane);
  if (lane == 63) s4[wv] = incl;
  __syncthreads();
  if (tid == 0) {
    int s = 0;
#pragma unroll
    for (int j = 0; j < 4; ++j) { int t = s4[j]; s4[j] = s; s += t; }
    btot[blockIdx.x] = s;
  }
  __syncthreads();
  if (i < N) offs[i] = s4[wv] + incl - x;
}

__global__ __launch_bounds__(256) void scan_tot_kernel(int* __restrict__ btot, int nb) {
  __shared__ int s4[4];
  __shared__ int carry;
  int tid = threadIdx.x;
  int lane = tid & 63, wv = tid >> 6;
  if (tid == 0) carry = 0;
  __syncthreads();
  for (int c0 = 0; c0 < nb; c0 += 256) {
    int i = c0 + tid;
    int x = (i < nb) ? btot[i] : 0;
    int incl = wave_incl_scan(x, lane);
    if (lane == 63) s4[wv] = incl;
    __syncthreads();
    if (tid == 0) {
      int s = 0;
#pragma unroll
      for (int j = 0; j < 4; ++j) { int t = s4[j]; s4[j] = s; s += t; }
    }
    __syncthreads();
    int base = carry + s4[wv];
    if (i < nb) btot[i] = base + incl - x;
    __syncthreads();
    if (tid == 255) carry = base + incl;
    __syncthreads();
  }
}

__global__ __launch_bounds__(256) void scan_add_kernel(int* __restrict__ offs,
                                                       const int* __restrict__ btot,
                                                       int N, int E) {
  int i = blockIdx.x * 256 + threadIdx.x;
  if (i < N) offs[i] += btot[blockIdx.x];
  if (i == 0) offs[N] = E;
}

// Fused: edge-bias MLP + CSR scatter of ONE 16B record per edge:
// {src, eb heads0-3 (fp8 e4m3 of eb*256), eb heads4-7, 0}. Single int4 store.
__global__ __launch_bounds__(256) void scatter_mlp_kernel(
    const int* __restrict__ dst, const int* __restrict__ src,
    const float* __restrict__ ef, const float* __restrict__ Wb1,
    const float* __restrict__ bb1, const float* __restrict__ Wb2,
    const float* __restrict__ bb2, const int* __restrict__ offs,
    int* __restrict__ cursor, i32x4* __restrict__ es16, int E) {
  __shared__ float w1[128], w2[64], b1[8], b2[8];
  int tid = threadIdx.x;
  if (tid < 128) w1[tid] = Wb1[tid];
  else if (tid < 192) w2[tid - 128] = Wb2[tid - 128];
  else if (tid < 200) b1[tid - 192] = bb1[tid - 192];
  else if (tid < 208) b2[tid - 200] = bb2[tid - 200];
  __syncthreads();

  int e = blockIdx.x * 256 + tid;
  if (e >= E) return;

  const f32x4v* p4 = (const f32x4v*)(ef + (size_t)e * 16);
  f32x4v f0 = __builtin_nontemporal_load(p4 + 0);
  f32x4v f1 = __builtin_nontemporal_load(p4 + 1);
  f32x4v f2 = __builtin_nontemporal_load(p4 + 2);
  f32x4v f3 = __builtin_nontemporal_load(p4 + 3);
  float x[16] = {f0[0], f0[1], f0[2], f0[3], f1[0], f1[1], f1[2], f1[3],
                 f2[0], f2[1], f2[2], f2[3], f3[0], f3[1], f3[2], f3[3]};

  float h[8];
#pragma unroll
  for (int j = 0; j < 8; ++j) h[j] = b1[j];
#pragma unroll
  for (int i = 0; i < 16; ++i) {
    float xi = x[i];
#pragma unroll
    for (int j = 0; j < 8; ++j) h[j] = fmaf(xi, w1[i * 8 + j], h[j]);
  }
#pragma unroll
  for (int j = 0; j < 8; ++j) h[j] = h[j] / (1.f + __expf(-h[j]));

  float o[8];
#pragma unroll
  for (int j = 0; j < 8; ++j) o[j] = b2[j];
#pragma unroll
  for (int jj = 0; jj < 8; ++jj) {
    float hj = h[jj];
#pragma unroll
    for (int j = 0; j < 8; ++j) o[j] = fmaf(hj, w2[jj * 8 + j], o[j]);
  }

  int lo = __builtin_amdgcn_cvt_pk_fp8_f32(o[0] * EB_SCALE, o[1] * EB_SCALE, 0, false);
  lo = __builtin_amdgcn_cvt_pk_fp8_f32(o[2] * EB_SCALE, o[3] * EB_SCALE, lo, true);
  int hi = __builtin_amdgcn_cvt_pk_fp8_f32(o[4] * EB_SCALE, o[5] * EB_SCALE, 0, false);
  hi = __builtin_amdgcn_cvt_pk_fp8_f32(o[6] * EB_SCALE, o[7] * EB_SCALE, hi, true);

  int d = dst[e];
  int p = offs[d] + atomicAdd(&cursor[d], 1);
  i32x4 rec;
  rec[0] = src[e]; rec[1] = lo; rec[2] = hi; rec[3] = 0;
  es16[p] = rec;
}

// ---------------------------------------------------------------------------
// Attention: 1 wave per dst node, 8 edges in flight, 8 lanes/edge.
// K/V gathered as fp8 e4m3 (256 B/edge); per-edge payload {src, eb} read as
// ONE sequential 16B record.
// ---------------------------------------------------------------------------
__global__ __launch_bounds__(256) void node_attn_kernel(
    const bf16* __restrict__ qb, const unsigned char* __restrict__ kv8,
    const i32x4* __restrict__ es16, const int* __restrict__ offs,
    bf16* __restrict__ agg, int Nn) {
  int n = blockIdx.x * 4 + (threadIdx.x >> 6);
  if (n >= Nn) return;
  int l = threadIdx.x & 63;
  int g = l >> 3;   // edge slot 0..7
  int il = l & 7;   // head index

  int s0 = offs[n], s1 = offs[n + 1];
  bf16* orow = agg + (size_t)n * HIDDEN + il * 16;
  if (s0 >= s1) {  // isolated node: zero output
    if (g == 0) {
      bf16x8 z = {};
      *(bf16x8*)(orow) = z;
      *(bf16x8*)(orow + 8) = z;
    }
    return;
  }

  const bf16* qrow = qb + (size_t)n * 128 + il * 16;
  bf16x8 qa = *(const bf16x8*)(qrow);
  bf16x8 qb8 = *(const bf16x8*)(qrow + 8);
  float qf[16];
#pragma unroll
  for (int j = 0; j < 8; ++j) {
    qf[j] = b2f(qa[j]) * QK_SCALE;
    qf[8 + j] = b2f(qb8[j]) * QK_SCALE;
  }

  float lsum = 0.f;
  float acc[16] = {};
  const int ebshift = (il & 2) << 3;  // 0 or 16

  for (int p0 = s0; p0 < s1; p0 += 8) {
    int p = p0 + g;
    bool valid = p < s1;
    int pc = valid ? p : s1 - 1;
    i32x4 rec = es16[pc];
    int cs = rec[0];
    unsigned ebw = (unsigned)((il < 4) ? rec[1] : rec[2]);
    f32x2 ebp = __builtin_amdgcn_cvt_pk_f32_fp8(ebw >> ebshift, false);
    float ebv = ((il & 1) ? ebp[1] : ebp[0]) * EB_INV;

    const unsigned char* kvrow = kv8 + (size_t)cs * 256 + il * 16;
    i32x4 kw = *(const i32x4*)(kvrow);
    i32x4 vw = *(const i32x4*)(kvrow + 128);

    float prod = 0.f;
#pragma unroll
    for (int w2 = 0; w2 < 4; ++w2) {
      f32x2 lo = __builtin_amdgcn_cvt_pk_f32_fp8(kw[w2], false);
      f32x2 hi = __builtin_amdgcn_cvt_pk_f32_fp8(kw[w2], true);
      prod = fmaf(qf[w2 * 4 + 0], lo[0], prod);
      prod = fmaf(qf[w2 * 4 + 1], lo[1], prod);
      prod = fmaf(qf[w2 * 4 + 2], hi[0], prod);
      prod = fmaf(qf[w2 * 4 + 3], hi[1], prod);
    }
    float pe = valid ? __expf(prod + ebv) : 0.f;
    lsum += pe;
#pragma unroll
    for (int w2 = 0; w2 < 4; ++w2) {
      f32x2 lo = __builtin_amdgcn_cvt_pk_f32_fp8(vw[w2], false);
      f32x2 hi = __builtin_amdgcn_cvt_pk_f32_fp8(vw[w2], true);
      acc[w2 * 4 + 0] = fmaf(pe, lo[0], acc[w2 * 4 + 0]);
      acc[w2 * 4 + 1] = fmaf(pe, lo[1], acc[w2 * 4 + 1]);
      acc[w2 * 4 + 2] = fmaf(pe, hi[0], acc[w2 * 4 + 2]);
      acc[w2 * 4 + 3] = fmaf(pe, hi[1], acc[w2 * 4 + 3]);
    }
  }

  // merge the 8 edge-slot partials (lanes xor 8,16,32 share the same head)
#pragma unroll
  for (int off = 8; off < 64; off <<= 1) {
    lsum += __shfl_xor(lsum, off, 64);
#pragma unroll
    for (int j = 0; j < 16; ++j) acc[j] += __shfl_xor(acc[j], off, 64);
  }

  if (g == 0) {
    float inv = (lsum > 0.f) ? 1.f / lsum : 0.f;
    bf16x8 o0, o1;
#pragma unroll
    for (int j = 0; j < 8; ++j) {
      o0[j] = f2b(acc[j] * inv);
      o1[j] = f2b(acc[8 + j] * inv);
    }
    *(bf16x8*)(orow) = o0;
    *(bf16x8*)(orow + 8) = o1;
  }
}

// ---------------------------------------------------------------------------
extern "C" void kernel_launch(void* const* d_in, const int* in_sizes, int n_in,
                              void* d_out, int out_size, void* d_ws, size_t ws_size,
                              hipStream_t stream) {
  const float* nf = (const float*)d_in[0];
  const int* ei = (const int*)d_in[1];
  const float* ef = (const float*)d_in[2];
  const float* Wq = (const float*)d_in[3];
  const float* bq = (const float*)d_in[4];
  const float* Wk = (const float*)d_in[5];
  const float* bk_ = (const float*)d_in[6];
  const float* Wv = (const float*)d_in[7];
  const float* bv = (const float*)d_in[8];
  const float* Wb1 = (const float*)d_in[9];
  const float* bb1 = (const float*)d_in[10];
  const float* Wb2 = (const float*)d_in[11];
  const float* bb2 = (const float*)d_in[12];
  const float* Wo = (const float*)d_in[13];
  const float* bo = (const float*)d_in[14];
  const float* Wf1 = (const float*)d_in[15];
  const float* bf1 = (const float*)d_in[16];
  const float* Wf2 = (const float*)d_in[17];
  const float* bf2 = (const float*)d_in[18];
  const float* g1 = (const float*)d_in[19];
  const float* be1 = (const float*)d_in[20];
  const float* g2 = (const float*)d_in[21];
  const float* be2 = (const float*)d_in[22];

  const int N = in_sizes[0] / HIDDEN;
  const int E = in_sizes[2] / EDGE_DIM;
  const int* srcA = ei;
  const int* dstA = ei + E;

  char* base = (char*)d_ws;
  size_t off = 0;
  auto alloc = [&](size_t bytes) {
    off = (off + 255) & ~(size_t)255;
    char* p = base + off;
    off += bytes;
    return p;
  };

  // region B: qb [N,128]bf16 + kv8 [N,256]u8 -> hbuf [N,256] bf16 overlay
  size_t qb_bytes = (size_t)N * 128 * 2;
  size_t kv_bytes = (size_t)N * 256;
  size_t hb_bytes = (size_t)N * 256 * 2;
  char* regB = alloc(hb_bytes > qb_bytes + kv_bytes ? hb_bytes : qb_bytes + kv_bytes);
  bf16* qb = (bf16*)regB;
  unsigned char* kv8 = (unsigned char*)(regB + qb_bytes);
  bf16* hbuf = (bf16*)regB;
  // standalone
  bf16* agg = (bf16*)alloc((size_t)N * HIDDEN * 2);
  bf16* x1b = (bf16*)alloc((size_t)N * HIDDEN * 2);
  i32x4* es16 = (i32x4*)alloc((size_t)E * 16);
  int* counts = (int*)alloc((size_t)N * 8);  // counts + cursor, one memset
  int* cursor = counts + N;
  int* offs = (int*)alloc((size_t)(N + 1) * 4);
  const int nb = (N + 255) / 256;
  int* btot = (int*)alloc((size_t)nb * 4);
  // weights
  bf16* Wqkv_t = (bf16*)alloc(384 * 128 * 2);
  bf16* Wo_t = (bf16*)alloc(128 * 128 * 2);
  bf16* Wf1_t = (bf16*)alloc(256 * 128 * 2);
  bf16* Wf2_t = (bf16*)alloc(128 * 256 * 2);
  float* bqkv = (float*)alloc(384 * 4);

  float* outp = (float*)d_out;
  const int mb64 = (N + 63) / 64;
  const int eblocks = (E + 255) / 256;

  conv_weights_kernel<<<512, 256, 0, stream>>>(Wq, Wk, Wv, bq, bk_, bv, Wo, Wf1, Wf2,
                                               Wqkv_t, Wo_t, Wf1_t, Wf2_t, bqkv);

  // fused QKV projection (single grid; A fragments register-resident x3 slices)
  mfma_gemm_qkv_kernel<<<mb64, 256, 0, stream>>>(nf, Wqkv_t, bqkv, qb, kv8, N);

  // CSR build + fused edge-bias MLP (single-pass 16B record scatter)
  hipMemsetAsync(counts, 0, (size_t)N * 8, stream);
  hist_kernel<<<eblocks, 256, 0, stream>>>(dstA, counts, E);
  scan_block_kernel<<<nb, 256, 0, stream>>>(counts, offs, btot, N);
  scan_tot_kernel<<<1, 256, 0, stream>>>(btot, nb);
  scan_add_kernel<<<nb, 256, 0, stream>>>(offs, btot, N, E);
  scatter_mlp_kernel<<<eblocks, 256, 0, stream>>>(dstA, srcA, ef, Wb1, bb1, Wb2, bb2,
                                                  offs, cursor, es16, E);

  // attention + aggregation (fp8 K/V gather, sequential es16 records)
  node_attn_kernel<<<(N + 3) / 4, 256, 0, stream>>>(qb, kv8, es16, offs, agg, N);

  // out proj + residual(fp32 nf) + LN1 -> x1b bf16 only (no fp32 copy)
  mfma_gemm_ln_kernel<128, 0><<<mb64, 256, 0, stream>>>(agg, Wo_t, bo, nf, g1, be1,
                                                        nullptr, x1b, N);

  // FFN1 (silu, bf16 out)
  mfma_gemm_kernel<128, 1, 1><<<dim3(2, mb64), 256, 0, stream>>>(
      x1b, Wf1_t, bf1, hbuf, N, 256);

  // FFN2 + residual(bf16 x1b) + LN2 -> output fp32
  mfma_gemm_ln_kernel<256, 1><<<mb64, 256, 0, stream>>>(hbuf, Wf2_t, bf2, x1b, g2, be2,
                                                        outp, nullptr, N);
}